// Round 6
// baseline (675.315 us; speedup 1.0000x reference)
//
#include <hip/hip_runtime.h>
#include <math.h>

// OuterLaplaceAggregation: complex first-order linear scan.
//   s_t = lambda * s_{t-1} + x_t,  s_{-1} = memory,  out = Re(s) [b,t,f,c]
//   lambda_{f,c} = exp(clip(a[f],-LIMIT,-1e-8) + i*b[c])
// B=8 T=512 F=1024 C=4.
//
// Single-kernel decoupled lookback: 1024 blocks (j,b,fblock) x 256 thr.
// All blocks co-resident (4 blocks/CU of 4 waves; capacity 8/CU) -> spin
// on predecessor flags is deadlock-free. x kept in registers; one HBM
// read of x, one NT write of out, 8 MB ws state round-trip via L2.

#define BB 8
#define TT 512
#define FF 1024
#define CC 4
#define NCH 32
#define LL (TT / NCH)          // 16
#define LIMIT_F 0.07664339751178941f
#define NBLK (NCH * BB * 4)    // 1024

typedef float v4f __attribute__((ext_vector_type(4)));

// ws state float index for chunk j, batch b, feature f (8 floats: 4x re,im)
#define WSE(j, b, f) ((((long long)(j) * BB + (b)) * FF + (f)) * 8)
#define WS_STATE_FLOATS ((long long)NCH * BB * FF * 8)   // 2,097,152 (8 MB)

__device__ __forceinline__ void make_lambda(const float* __restrict__ a_vec,
                                            const float* __restrict__ b_vec,
                                            int f, float lr[CC], float li[CC])
{
    const float af = fminf(fmaxf(a_vec[f], -LIMIT_F), -1e-8f);
    const float ea = expf(af);
#pragma unroll
    for (int c = 0; c < CC; ++c) {
        float s, cz;
        sincosf(b_vec[c], &s, &cz);
        lr[c] = ea * cz;
        li[c] = ea * s;
    }
}

__global__ __launch_bounds__(256) void
scan_lookback_kernel(const float* __restrict__ x,
                     const float* __restrict__ mem_r,
                     const float* __restrict__ mem_i,
                     const float* __restrict__ a_vec,
                     const float* __restrict__ b_vec,
                     float* __restrict__ ws_e,     // 8 MB states
                     int* __restrict__ flags,      // NBLK ints, pre-zeroed
                     float* __restrict__ out,
                     long long x_lim, long long mem_lim,
                     long long out4_lim, long long imag_off4)
{
    const int tid = threadIdx.x;
    const int bid = blockIdx.x;          // [0, 1024)
    const int fb = bid & 3;
    const int b  = (bid >> 2) & (BB - 1);
    const int j  = bid >> 5;             // 0..31
    const int f  = fb * 256 + tid;

    float lr[CC], li[CC];
    make_lambda(a_vec, b_vec, f, lr, li);

    // ---- local chunk scan, x cached in registers ----
    const long long xbase = ((long long)b * TT + j * LL) * FF + f;
    const bool xok = (xbase + (long long)(LL - 1) * FF) < x_lim;

    float xv[LL];
#pragma unroll
    for (int t = 0; t < LL; ++t)
        xv[t] = xok ? x[xbase + (long long)t * FF] : 0.f;

    float er[CC] = {0.f, 0.f, 0.f, 0.f}, ei[CC] = {0.f, 0.f, 0.f, 0.f};
#pragma unroll
    for (int t = 0; t < LL; ++t) {
#pragma unroll
        for (int c = 0; c < CC; ++c) {
            const float nr = fmaf(lr[c], er[c], fmaf(-li[c], ei[c], xv[t]));
            const float ni = fmaf(li[c], er[c], lr[c] * ei[c]);
            er[c] = nr; ei[c] = ni;
        }
    }

    // ---- publish chunk aggregate (regular stores -> L2-visible) ----
    {
        const long long w = WSE(j, b, f);
        v4f* w4 = (v4f*)(ws_e + w);
        w4[0] = (v4f){er[0], ei[0], er[1], ei[1]};
        w4[1] = (v4f){er[2], ei[2], er[3], ei[3]};
    }
    __threadfence();          // device-scope: make state visible
    __syncthreads();          // all threads' stores done before flag
    if (tid == 0)
        __hip_atomic_store(&flags[bid], 1, __ATOMIC_RELEASE,
                           __HIP_MEMORY_SCOPE_AGENT);

    // ---- lookback: seed = memory, fold aggregates of chunks 0..j-1 ----
    const float af = fminf(fmaxf(a_vec[f], -LIMIT_F), -1e-8f);
    const float eaL = expf(af * (float)LL);
    float lLr[CC], lLi[CC];
#pragma unroll
    for (int c = 0; c < CC; ++c) {
        float s, cz;
        sincosf(b_vec[c] * (float)LL, &s, &cz);
        lLr[c] = eaL * cz;
        lLi[c] = eaL * s;
    }

    float sr[CC], si[CC];
#pragma unroll
    for (int c = 0; c < CC; ++c) {
        const long long m = (long long)(b * FF + f) * CC + c;
        sr[c] = (m < mem_lim) ? mem_r[m] : 0.f;
        si[c] = (m < mem_lim) ? mem_i[m] : 0.f;
    }

    for (int i = 0; i < j; ++i) {         // block-uniform trip count
        const int pf = (i << 5) | (b << 2) | fb;   // predecessor block id
        int n = 0;
        while (__hip_atomic_load(&flags[pf], __ATOMIC_ACQUIRE,
                                 __HIP_MEMORY_SCOPE_AGENT) == 0 &&
               n < (1 << 20)) { __builtin_amdgcn_s_sleep(2); ++n; }

        const long long w = WSE(i, b, f);
        const v4f* w4 = (const v4f*)(ws_e + w);
        const v4f A = w4[0], Bv = w4[1];
        const float ar[CC] = {A.x, A.z, Bv.x, Bv.z};
        const float ai[CC] = {A.y, A.w, Bv.y, Bv.w};
#pragma unroll
        for (int c = 0; c < CC; ++c) {
            const float nr = fmaf(lLr[c], sr[c], fmaf(-lLi[c], si[c], ar[c]));
            const float ni = fmaf(lLi[c], sr[c], fmaf(lLr[c], si[c], ai[c]));
            sr[c] = nr; si[c] = ni;
        }
    }

    // ---- replay scan from registers, NT-store output ----
    v4f* out4 = (v4f*)out;
    const long long obase = xbase;        // float4 index: (b*T + t)*F + f
    const bool rok = (obase + (long long)(LL - 1) * FF) < out4_lim;
    const bool iok = (imag_off4 > 0) &&
                     ((obase + imag_off4 + (long long)(LL - 1) * FF) < out4_lim);

#pragma unroll
    for (int t = 0; t < LL; ++t) {
#pragma unroll
        for (int c = 0; c < CC; ++c) {
            const float nr = fmaf(lr[c], sr[c], fmaf(-li[c], si[c], xv[t]));
            const float ni = fmaf(li[c], sr[c], lr[c] * si[c]);
            sr[c] = nr; si[c] = ni;
        }
        if (rok) __builtin_nontemporal_store(
            (v4f){sr[0], sr[1], sr[2], sr[3]},
            &out4[obase + (long long)t * FF]);
        if (iok) __builtin_nontemporal_store(
            (v4f){si[0], si[1], si[2], si[3]},
            &out4[obase + imag_off4 + (long long)t * FF]);
    }
}

// ---- fallback: single-pass, thread = (b, f), if ws too small ----
__global__ __launch_bounds__(256) void
fb_kernel(const float* __restrict__ x,
          const float* __restrict__ mem_r,
          const float* __restrict__ mem_i,
          const float* __restrict__ a_vec,
          const float* __restrict__ b_vec,
          float* __restrict__ out,
          long long x_lim, long long mem_lim, long long out4_lim,
          long long imag_off4)
{
    const int g = blockIdx.x * 256 + threadIdx.x;   // [0, 8192)
    const int f = g & (FF - 1);
    const int b = g >> 10;

    float lr[CC], li[CC];
    make_lambda(a_vec, b_vec, f, lr, li);

    float sr[CC], si[CC];
#pragma unroll
    for (int c = 0; c < CC; ++c) {
        const long long m = (long long)(b * FF + f) * CC + c;
        sr[c] = (m < mem_lim) ? mem_r[m] : 0.f;
        si[c] = (m < mem_lim) ? mem_i[m] : 0.f;
    }

    const long long xbase = (long long)b * TT * FF + f;
    const bool xok = (xbase + (long long)(TT - 1) * FF) < x_lim;
    v4f* out4 = (v4f*)out;
    const bool rok = (xbase + (long long)(TT - 1) * FF) < out4_lim;
    const bool iok = (imag_off4 > 0) &&
                     ((xbase + imag_off4 + (long long)(TT - 1) * FF) < out4_lim);

    for (int t = 0; t < TT; ++t) {
        const float xv = xok ? x[xbase + (long long)t * FF] : 0.f;
#pragma unroll
        for (int c = 0; c < CC; ++c) {
            const float nr = fmaf(lr[c], sr[c], fmaf(-li[c], si[c], xv));
            const float ni = fmaf(li[c], sr[c], lr[c] * si[c]);
            sr[c] = nr; si[c] = ni;
        }
        if (rok) out4[xbase + (long long)t * FF] =
            (v4f){sr[0], sr[1], sr[2], sr[3]};
        if (iok) out4[xbase + imag_off4 + (long long)t * FF] =
            (v4f){si[0], si[1], si[2], si[3]};
    }
}

extern "C" void kernel_launch(void* const* d_in, const int* in_sizes, int n_in,
                              void* d_out, int out_size, void* d_ws, size_t ws_size,
                              hipStream_t stream)
{
    const float* x     = (const float*)d_in[0];
    const float* mem_r = (const float*)d_in[1];
    const float* mem_i = (const float*)d_in[2];
    const float* a_vec = (const float*)d_in[3];
    const float* b_vec = (const float*)d_in[4];
    float* out = (float*)d_out;

    const long long x_lim   = (long long)in_sizes[0];       // 4,194,304
    const long long mem_lim = (long long)in_sizes[1];       // 32,768
    const long long BTFC = (long long)BB * TT * FF * CC;    // 16,777,216
    const long long out4_lim = (long long)out_size / 4;
    const long long imag_off4 = ((long long)out_size >= 2 * BTFC) ? (BTFC / 4) : 0;

    const size_t need = (size_t)(WS_STATE_FLOATS * sizeof(float)) +
                        (size_t)NBLK * sizeof(int);
    if (ws_size >= need) {
        float* ws_e = (float*)d_ws;
        int* flags = (int*)(ws_e + WS_STATE_FLOATS);
        hipMemsetAsync(flags, 0, (size_t)NBLK * sizeof(int), stream);
        scan_lookback_kernel<<<NBLK, 256, 0, stream>>>(
            x, mem_r, mem_i, a_vec, b_vec, ws_e, flags, out,
            x_lim, mem_lim, out4_lim, imag_off4);
    } else {
        fb_kernel<<<(BB * FF) / 256, 256, 0, stream>>>(
            x, mem_r, mem_i, a_vec, b_vec, out,
            x_lim, mem_lim, out4_lim, imag_off4);
    }
}

// Round 7
// 93.177 us; speedup vs baseline: 7.2477x; 7.2477x over previous
//
#include <hip/hip_runtime.h>
#include <math.h>

// OuterLaplaceAggregation: complex first-order linear scan.
//   s_t = lambda * s_{t-1} + x_t,  s_{-1} = memory,  out = Re(s) [b,t,f,c]
//   lambda_{f,c} = exp(clip(a[f],-LIMIT,-1e-8) + i*b[c])
// B=8 T=512 F=1024 C=4.
//
// SINGLE kernel, LDS-based chunked scan. Block = (b, 16-feature group),
// 512 threads = 16 f x 32 chunks (LL=16 steps each). Phase A: local chunk
// scan with x in registers -> aggregate to LDS. Phase B: fold memory seed
// + predecessor aggregates (lambda^16 via 4 complex squarings). Phase C:
// replay from registers, nontemporal float4 stores. No global workspace,
// no cross-block sync. 512 blocks = 2/CU, 16 waves/CU.

#define BB 8
#define TT 512
#define FF 1024
#define CC 4
#define NCH 32
#define LL (TT / NCH)          // 16
#define FG 16                  // features per block
#define LIMIT_F 0.07664339751178941f

typedef float v4f __attribute__((ext_vector_type(4)));

__global__ __launch_bounds__(512) void
scan_lds_kernel(const float* __restrict__ x,
                const float* __restrict__ mem_r,
                const float* __restrict__ mem_i,
                const float* __restrict__ a_vec,
                const float* __restrict__ b_vec,
                float* __restrict__ out,
                long long x_lim, long long mem_lim,
                long long out4_lim, long long imag_off4)
{
    const int tid = threadIdx.x;           // [0,512)
    const int bid = blockIdx.x;            // [0,512)
    const int fg  = bid & 63;              // feature group
    const int b   = bid >> 6;              // batch
    const int fl  = tid & (FG - 1);        // 0..15
    const int j   = tid >> 4;              // chunk 0..31
    const int f   = fg * FG + fl;

    // lambda per c
    const float af = fminf(fmaxf(a_vec[f], -LIMIT_F), -1e-8f);
    const float ea = expf(af);
    float lr[CC], li[CC];
#pragma unroll
    for (int c = 0; c < CC; ++c) {
        float s, cz;
        sincosf(b_vec[c], &s, &cz);
        lr[c] = ea * cz;
        li[c] = ea * s;
    }

    // ---- load this chunk's x into registers ----
    const long long xbase = ((long long)b * TT + j * LL) * FF + f;
    const bool xok = (xbase + (long long)(LL - 1) * FF) < x_lim;
    float xv[LL];
#pragma unroll
    for (int t = 0; t < LL; ++t)
        xv[t] = xok ? x[xbase + (long long)t * FF] : 0.f;

    // ---- phase A: chunk-local scan, zero seed ----
    float er[CC] = {0.f, 0.f, 0.f, 0.f}, ei[CC] = {0.f, 0.f, 0.f, 0.f};
#pragma unroll
    for (int t = 0; t < LL; ++t) {
#pragma unroll
        for (int c = 0; c < CC; ++c) {
            const float nr = fmaf(lr[c], er[c], fmaf(-li[c], ei[c], xv[t]));
            const float ni = fmaf(li[c], er[c], lr[c] * ei[c]);
            er[c] = nr; ei[c] = ni;
        }
    }

    // aggregate exchange via LDS: agg[j][fl] = 4x (re,im)
    __shared__ float agg[NCH][FG][8];
    {
        v4f* w4 = (v4f*)&agg[j][fl][0];
        w4[0] = (v4f){er[0], ei[0], er[1], ei[1]};
        w4[1] = (v4f){er[2], ei[2], er[3], ei[3]};
    }
    __syncthreads();

    // ---- phase B: lambda^LL via 4 complex squarings; fold predecessors ----
    float lLr[CC], lLi[CC];
#pragma unroll
    for (int c = 0; c < CC; ++c) {
        float pr = lr[c], pi = li[c];
#pragma unroll
        for (int k = 0; k < 4; ++k) {      // ^2 four times -> ^16
            const float nr = fmaf(pr, pr, -(pi * pi));
            const float ni = 2.f * pr * pi;
            pr = nr; pi = ni;
        }
        lLr[c] = pr; lLi[c] = pi;
    }

    float sr[CC], si[CC];
#pragma unroll
    for (int c = 0; c < CC; ++c) {
        const long long m = (long long)(b * FF + f) * CC + c;
        sr[c] = (m < mem_lim) ? mem_r[m] : 0.f;
        si[c] = (m < mem_lim) ? mem_i[m] : 0.f;
    }

    for (int i = 0; i < j; ++i) {          // <=31 folds, LDS reads
        const v4f* r4 = (const v4f*)&agg[i][fl][0];
        const v4f A = r4[0], Bv = r4[1];
        const float ar[CC] = {A.x, A.z, Bv.x, Bv.z};
        const float ai[CC] = {A.y, A.w, Bv.y, Bv.w};
#pragma unroll
        for (int c = 0; c < CC; ++c) {
            const float nr = fmaf(lLr[c], sr[c], fmaf(-lLi[c], si[c], ar[c]));
            const float ni = fmaf(lLi[c], sr[c], fmaf(lLr[c], si[c], ai[c]));
            sr[c] = nr; si[c] = ni;
        }
    }

    // ---- phase C: replay from registers, NT-store ----
    v4f* out4 = (v4f*)out;
    const long long obase = xbase;         // float4 index: (b*T+t)*F + f
    const bool rok = (obase + (long long)(LL - 1) * FF) < out4_lim;
    const bool iok = (imag_off4 > 0) &&
                     ((obase + imag_off4 + (long long)(LL - 1) * FF) < out4_lim);

#pragma unroll
    for (int t = 0; t < LL; ++t) {
#pragma unroll
        for (int c = 0; c < CC; ++c) {
            const float nr = fmaf(lr[c], sr[c], fmaf(-li[c], si[c], xv[t]));
            const float ni = fmaf(li[c], sr[c], lr[c] * si[c]);
            sr[c] = nr; si[c] = ni;
        }
        if (rok) __builtin_nontemporal_store(
            (v4f){sr[0], sr[1], sr[2], sr[3]},
            &out4[obase + (long long)t * FF]);
        if (iok) __builtin_nontemporal_store(
            (v4f){si[0], si[1], si[2], si[3]},
            &out4[obase + imag_off4 + (long long)t * FF]);
    }
}

extern "C" void kernel_launch(void* const* d_in, const int* in_sizes, int n_in,
                              void* d_out, int out_size, void* d_ws, size_t ws_size,
                              hipStream_t stream)
{
    const float* x     = (const float*)d_in[0];
    const float* mem_r = (const float*)d_in[1];
    const float* mem_i = (const float*)d_in[2];
    const float* a_vec = (const float*)d_in[3];
    const float* b_vec = (const float*)d_in[4];
    float* out = (float*)d_out;

    const long long x_lim   = (long long)in_sizes[0];       // 4,194,304
    const long long mem_lim = (long long)in_sizes[1];       // 32,768
    const long long BTFC = (long long)BB * TT * FF * CC;    // 16,777,216
    const long long out4_lim = (long long)out_size / 4;
    const long long imag_off4 = ((long long)out_size >= 2 * BTFC) ? (BTFC / 4) : 0;

    const int grid = BB * (FF / FG);       // 512 blocks
    scan_lds_kernel<<<grid, 512, 0, stream>>>(
        x, mem_r, mem_i, a_vec, b_vec, out,
        x_lim, mem_lim, out4_lim, imag_off4);
}